// Round 11
// baseline (146.207 us; speedup 1.0000x reference)
//
#include <hip/hip_runtime.h>

typedef _Float16 f16;
typedef _Float16 f16x8 __attribute__((ext_vector_type(8)));
typedef __bf16 bf16x8 __attribute__((ext_vector_type(8)));
typedef float floatx4 __attribute__((ext_vector_type(4)));
typedef unsigned short u16;

#define B_N   8
#define T_SEQ 4096
#define DIM   64
#define QT    64     // q rows per attn block (r10's QT=32 regressed: overhead-bound)
#define NIT   32     // 32 basic tiles of 128 keys; processed 2 per barrier (16 super-iters)
#define XSTR  72     // prep LDS row stride in u16
#define LOG2E 1.44269504f
#define FRAG  512    // fragment = 512 u16 (1 KB): lane holds its 8 u16 at lane*8

#if __has_builtin(__builtin_amdgcn_exp2f)
#define EXP2(x) __builtin_amdgcn_exp2f(x)
#else
#define EXP2(x) exp2f(x)
#endif

typedef __attribute__((address_space(1))) const void gvoid;
typedef __attribute__((address_space(3))) void svoid;

// ---- prep v2: 32-row blocks, wave-specialized roles. Unchanged from round 6. ----
__launch_bounds__(256, 4)
__global__ void prep_kernel(const float* __restrict__ X, const float* __restrict__ W,
                            u16* __restrict__ Kswz, u16* __restrict__ Qswz,
                            u16* __restrict__ Vswz) {
  __shared__ __attribute__((aligned(16))) u16 Xs[32 * XSTR];      // f16 X tile [t][d]
  __shared__ __attribute__((aligned(16))) u16 Wt[DIM * XSTR];     // f16 W^T [e][d]
  __shared__ __attribute__((aligned(16))) u16 Qs[2][16 * XSTR];   // f16 Q rows (per Q-wave)
  const int tid = threadIdx.x;
  const int lane = tid & 63, w = tid >> 6, qd = lane >> 4, ln = lane & 15;
  const int b = blockIdx.y;
  const int tau = blockIdx.x;                 // global 32-row tile index, 0..127
  const long xbase = ((long)b * T_SEQ + tau * 32) * DIM;

  {
    // X tile: 32 rows x 64 cols, 8 f32 per thread
    const int r = tid >> 3, c0 = (tid & 7) * 8;
    float v[8];
    *(float4*)&v[0] = *(const float4*)(X + xbase + (long)r * DIM + c0);
    *(float4*)&v[4] = *(const float4*)(X + xbase + (long)r * DIM + c0 + 4);
    u16 h[8];
#pragma unroll
    for (int j = 0; j < 8; j++) h[j] = __builtin_bit_cast(u16, (f16)v[j]);
    *(uint4*)&Xs[r * XSTR + c0] = *(uint4*)&h[0];
    // W: 64x64, 16 f32 per thread, transposed scalar stores
    const int r2 = tid >> 2, c2 = (tid & 3) * 16;
    float wv[16];
#pragma unroll
    for (int i = 0; i < 4; i++)
      *(float4*)&wv[i * 4] = *(const float4*)(W + r2 * DIM + c2 + i * 4);
#pragma unroll
    for (int j = 0; j < 16; j++) Wt[(c2 + j) * XSTR + r2] = __builtin_bit_cast(u16, (f16)wv[j]);
  }
  __syncthreads();

  if (w == 0) {
    // K fragments, SLOT-PERMUTED: frag (tau, ct), lane ln reads tile-local row
    // krow = (ln>>2)*8 + ct*4 + (ln&3).
#pragma unroll
    for (int ct = 0; ct < 2; ct++) {
      const int krow = (ln >> 2) * 8 + ct * 4 + (ln & 3);
      const long F = ((long)b * 128 + tau) * 2 + ct;
#pragma unroll
      for (int ks = 0; ks < 2; ks++) {
        f16x8 kv = *(const f16x8*)&Xs[krow * XSTR + ks * 32 + qd * 8];
        *(f16x8*)(Kswz + (F * 2 + ks) * FRAG + lane * 8) = kv;
      }
    }
    // V d-block 0
    {
      const long Cb = (long)b * 4 + 0;
      bf16x8 vv;
#pragma unroll
      for (int j = 0; j < 8; j++) {
        f16 hv = __builtin_bit_cast(f16, Xs[(qd * 8 + j) * XSTR + 0 * 16 + ln]);
        vv[j] = (__bf16)(float)hv;
      }
      *(bf16x8*)(Vswz + (Cb * (T_SEQ / 32) + tau) * FRAG + lane * 8) = vv;
    }
  } else if (w == 1) {
    // V d-blocks 1..3
#pragma unroll
    for (int db = 1; db < 4; db++) {
      const long Cb = (long)b * 4 + db;
      bf16x8 vv;
#pragma unroll
      for (int j = 0; j < 8; j++) {
        f16 hv = __builtin_bit_cast(f16, Xs[(qd * 8 + j) * XSTR + db * 16 + ln]);
        vv[j] = (__bf16)(float)hv;
      }
      *(bf16x8*)(Vswz + (Cb * (T_SEQ / 32) + tau) * FRAG + lane * 8) = vv;
    }
  } else {
    // Q rows (w-2)*16 .. +16: X@W via MFMA, scale by log2e, emit A-fragments
    const int h2 = w - 2;             // 0..1
    const int rq = h2 * 16;
    floatx4 acc[4];
#pragma unroll
    for (int ct = 0; ct < 4; ct++) acc[ct] = (floatx4)0.0f;
#pragma unroll
    for (int ks = 0; ks < 2; ks++) {
      f16x8 aX = *(const f16x8*)&Xs[(rq + ln) * XSTR + ks * 32 + qd * 8];
#pragma unroll
      for (int ct = 0; ct < 4; ct++) {
        f16x8 bW = *(const f16x8*)&Wt[(ct * 16 + ln) * XSTR + ks * 32 + qd * 8];
        acc[ct] = __builtin_amdgcn_mfma_f32_16x16x32_f16(aX, bW, acc[ct], 0, 0, 0);
      }
    }
#pragma unroll
    for (int ct = 0; ct < 4; ct++)
#pragma unroll
      for (int r = 0; r < 4; r++)
        Qs[h2][(qd * 4 + r) * XSTR + ct * 16 + ln] =
            __builtin_bit_cast(u16, (f16)(acc[ct][r] * LOG2E));
    // wave-local rows: no barrier needed
    const long R = (long)b * (T_SEQ / 16) + tau * 2 + h2;
#pragma unroll
    for (int ks = 0; ks < 2; ks++) {
      f16x8 qv = *(const f16x8*)&Qs[h2][ln * XSTR + ks * 32 + qd * 8];
      *(f16x8*)(Qswz + (R * 2 + ks) * FRAG + lane * 8) = qv;
    }
  }
}

// ---- main, ROUND 11: r9 structure (best: 46.2 us) + 2-tiles-per-barrier.
// r10 lesson: the kernel is per-wave-OVERHEAD-bound (halving work/wave at
// constant overhead made it 42% slower). So amortize: one barrier + one
// stage burst + one loop iteration per 256 keys (2 basic tiles) instead of
// 128. K in 4 x 16 KB LDS buffers (pair-flip dbuf); V direct from L2.
// QK(t+1) MFMAs are independent of exp(t) VALU -> scheduler can overlap
// pipes inside the super-iteration. bV(t+1) loaded after PV(t) to cap
// register pressure (~104 live < 128 cap of (512,4); r7 spill mode avoided).
// Rule #20: all register-array indices compile-time.
__launch_bounds__(512, 4)
__global__ void attn_kernel(const u16* __restrict__ Kswz, const u16* __restrict__ Qswz,
                            const u16* __restrict__ Vswz, float* __restrict__ out) {
  // smem: 4 K buffers x 16 KB (pairs flip); epilogue Opart (34816 B) aliases
  __shared__ __attribute__((aligned(16))) char smem[65536];
  __shared__ float lpart[8][32];
  float* Opart = (float*)smem;

  const int tid = threadIdx.x;
  const int lane = tid & 63;
  const int w = tid >> 6;           // 0..7
  const int qd = lane >> 4;
  const int ln = lane & 15;
  const int wg = w >> 2;            // q-group
  const int wk = w & 3;             // key subgroup
  const int bid = blockIdx.x;
  const int b = bid & 7;            // batch == XCD for L2 affinity
  const int q0 = (bid >> 3) * QT;
  const long bbase = (long)b * T_SEQ * DIM;

  // Q B-fragments pinned: 32 rows x 64 d for this q-group
  f16x8 aQ[2][2];
#pragma unroll
  for (int rb = 0; rb < 2; rb++)
#pragma unroll
    for (int ks = 0; ks < 2; ks++)
      aQ[rb][ks] = *(const f16x8*)(Qswz +
          (((long)b * (T_SEQ / 16) + (q0 >> 4) + wg * 2 + rb) * 2 + ks) * FRAG + lane * 8);

  // K stage source: wave w stages bytes w*2048..+2048 of each 16 KB tile-group
  const char* gKw = (const char*)Kswz + (long)b * 524288 + (long)w * 2048 + lane * 16;
  // V direct source: frag (db, tile t*4+wk) at b*524288 + db*131072 + (t*4+wk)*1024
  const char* gV = (const char*)Vswz + (long)b * 524288 + (long)wk * 1024 + lane * 16;

#define STAGE(dst, t)                                                                   \
  do {                                                                                  \
    const char* g = gKw + (long)(t) * 16384;                                            \
    char* l = (dst) + w * 2048;                                                         \
    __builtin_amdgcn_global_load_lds((gvoid*)(g), (svoid*)(l), 16, 0, 0);               \
    __builtin_amdgcn_global_load_lds((gvoid*)(g + 1024), (svoid*)(l + 1024), 16, 0, 0); \
  } while (0)

// one 128-key tile: K ds_read from KBUF, QK, exp -> pk, PV with given bV set
#define TILE(KBUF, tv, BV)                                                              \
  do {                                                                                  \
    const char* Kb_ = (KBUF) + wk * 4096;                                               \
    f16x8 bK_[2][2];                                                                    \
    _Pragma("unroll") for (int ct = 0; ct < 2; ct++)                                    \
      _Pragma("unroll") for (int ks = 0; ks < 2; ks++)                                  \
        bK_[ct][ks] = *(const f16x8*)(Kb_ + (ct * 2 + ks) * 1024 + lane * 16);          \
    floatx4 St_[2][2];                                                                  \
    _Pragma("unroll") for (int ct = 0; ct < 2; ct++)                                    \
      _Pragma("unroll") for (int rb = 0; rb < 2; rb++) St_[ct][rb] = (floatx4)0.0f;     \
    __builtin_amdgcn_s_setprio(1);                                                      \
    _Pragma("unroll") for (int ks = 0; ks < 2; ks++)                                    \
      _Pragma("unroll") for (int ct = 0; ct < 2; ct++)                                  \
        _Pragma("unroll") for (int rb = 0; rb < 2; rb++)                                \
          St_[ct][rb] = __builtin_amdgcn_mfma_f32_16x16x32_f16(bK_[ct][ks], aQ[rb][ks], \
                                                               St_[ct][rb], 0, 0, 0);   \
    __builtin_amdgcn_s_setprio(0);                                                      \
    bf16x8 pk_[2];                                                                      \
    _Pragma("unroll") for (int rb = 0; rb < 2; rb++) {                                  \
      float ps = 0.f;                                                                   \
      _Pragma("unroll") for (int ct = 0; ct < 2; ct++)                                  \
        _Pragma("unroll") for (int r = 0; r < 4; r++) {                                 \
          float p = EXP2(St_[ct][rb][r]);                                               \
          ps += p;                                                                      \
          pk_[rb][ct * 4 + r] = (__bf16)p;                                              \
        }                                                                               \
      lacc[rb] += ps;                                                                   \
    }                                                                                   \
    __builtin_amdgcn_s_setprio(1);                                                      \
    _Pragma("unroll") for (int rb = 0; rb < 2; rb++)                                    \
      _Pragma("unroll") for (int db = 0; db < 4; db++)                                  \
        O[rb][db] = __builtin_amdgcn_mfma_f32_16x16x32_bf16(pk_[rb], BV[db],            \
                                                            O[rb][db], 0, 0, 0);        \
    __builtin_amdgcn_s_setprio(0);                                                      \
  } while (0)

#define LOADV(BV, tv)                                                                   \
  do {                                                                                  \
    _Pragma("unroll") for (int db = 0; db < 4; db++)                                    \
      BV[db] = *(const bf16x8*)(gV + (long)(tv) * 4096 + (long)db * 131072);            \
  } while (0)

  floatx4 O[2][4];                  // [q 16-block][d 16-block], 32q x 64d per wave
  float lacc[2] = {0.f, 0.f};
#pragma unroll
  for (int rb = 0; rb < 2; rb++)
#pragma unroll
    for (int db = 0; db < 4; db++) O[rb][db] = (floatx4)0.0f;

  // prologue: stage tiles 0,1 into buffers 0,1
  STAGE(smem, 0);
  STAGE(smem + 16384, 1);
  __syncthreads();

#pragma unroll 1
  for (int j = 0; j < NIT / 2; j++) {
    const int a = 2 * j;
    char* cur = smem + (j & 1) * 32768;
    char* nxt = smem + ((j & 1) ^ 1) * 32768;
    // stage next pair (oldest in vmcnt queue after V(a) below is fine:
    // barrier at end drains everything anyway)
    if (j + 1 < NIT / 2) {
      STAGE(nxt, a + 2);
      STAGE(nxt + 16384, a + 3);
    }
    bf16x8 bV0[4], bV1[4];
    LOADV(bV0, a);
    TILE(cur, a, bV0);
    LOADV(bV1, a + 1);               // issued after PV(a): latency covered by QK/exp(a+1)
    TILE(cur + 16384, a + 1, bV1);
    __syncthreads();                 // staged pair landed; cur pair reads done
  }

  // l partials: reduce across qd lanes; lpart[w][q-local 0..31]
#pragma unroll
  for (int rb = 0; rb < 2; rb++) {
    float v = lacc[rb];
    v += __shfl_xor(v, 16, 64);
    v += __shfl_xor(v, 32, 64);
    if (qd == 0) lpart[w][rb * 16 + ln] = v;
  }

  // epilogue: FULLY UNROLLED (rule #20: runtime rb would home O in scratch)
#pragma unroll
  for (int rb = 0; rb < 2; rb++) {
    __syncthreads();  // rb=0: lpart published + last K reads done; rb=1: prior reads done
#pragma unroll
    for (int db = 0; db < 4; db++)
#pragma unroll
      for (int r = 0; r < 4; r++)
        Opart[(w * 16 + qd * 4 + r) * 68 + db * 16 + ln] = O[rb][db][r];
    __syncthreads();
    const int wg2 = tid >> 8;         // 0..1
    const int q2 = (tid >> 4) & 15;   // 0..15
    const int d0 = (tid & 15) * 4;    // 0..60
    float4 s = *(const float4*)&Opart[((wg2 * 4 + 0) * 16 + q2) * 68 + d0];
    const float4 s1 = *(const float4*)&Opart[((wg2 * 4 + 1) * 16 + q2) * 68 + d0];
    const float4 s2 = *(const float4*)&Opart[((wg2 * 4 + 2) * 16 + q2) * 68 + d0];
    const float4 s3 = *(const float4*)&Opart[((wg2 * 4 + 3) * 16 + q2) * 68 + d0];
    float l = lpart[wg2 * 4 + 0][rb * 16 + q2] + lpart[wg2 * 4 + 1][rb * 16 + q2] +
              lpart[wg2 * 4 + 2][rb * 16 + q2] + lpart[wg2 * 4 + 3][rb * 16 + q2];
    const float inv = 1.0f / l;
    float4 o;
    o.x = (s.x + s1.x + s2.x + s3.x) * inv;
    o.y = (s.y + s1.y + s2.y + s3.y) * inv;
    o.z = (s.z + s1.z + s2.z + s3.z) * inv;
    o.w = (s.w + s1.w + s2.w + s3.w) * inv;
    *(float4*)(out + bbase + (long)(q0 + wg2 * 32 + rb * 16 + q2) * DIM + d0) = o;
  }
#undef LOADV
#undef TILE
#undef STAGE
}

extern "C" void kernel_launch(void* const* d_in, const int* in_sizes, int n_in,
                              void* d_out, int out_size, void* d_ws, size_t ws_size,
                              hipStream_t stream) {
  const float* X = (const float*)d_in[0];
  const float* W = (const float*)d_in[1];
  float* out = (float*)d_out;
  const size_t SZ = (size_t)B_N * T_SEQ * DIM * 2;  // 4 MB per u16 array
  u16* Kswz = (u16*)d_ws;
  u16* Qswz = (u16*)((char*)d_ws + SZ);
  u16* Vswz = (u16*)((char*)d_ws + 2 * SZ);
  prep_kernel<<<dim3(T_SEQ / 32, B_N), 256, 0, stream>>>(X, W, Kswz, Qswz, Vswz);
  attn_kernel<<<dim3(B_N * (T_SEQ / QT)), 512, 0, stream>>>(Kswz, Qswz, Vswz, out);
}

// Round 12
// 113.641 us; speedup vs baseline: 1.2866x; 1.2866x over previous
//
#include <hip/hip_runtime.h>

typedef _Float16 f16;
typedef _Float16 f16x8 __attribute__((ext_vector_type(8)));
typedef __bf16 bf16x8 __attribute__((ext_vector_type(8)));
typedef float floatx4 __attribute__((ext_vector_type(4)));
typedef unsigned short u16;

#define B_N   8
#define T_SEQ 4096
#define DIM   64
#define QT    64     // q rows per attn block
#define NIT   32     // 32 basic tiles of 128 keys; 2 per barrier (16 super-iters)
#define XSTR  72     // prep LDS row stride in u16
#define LOG2E 1.44269504f
#define FRAG  512    // fragment = 512 u16 (1 KB): lane holds its 8 u16 at lane*8

#if __has_builtin(__builtin_amdgcn_exp2f)
#define EXP2(x) __builtin_amdgcn_exp2f(x)
#else
#define EXP2(x) exp2f(x)
#endif

typedef __attribute__((address_space(1))) const void gvoid;
typedef __attribute__((address_space(3))) void svoid;

// ---- prep v2: 32-row blocks, wave-specialized roles. Unchanged from round 6. ----
__launch_bounds__(256, 4)
__global__ void prep_kernel(const float* __restrict__ X, const float* __restrict__ W,
                            u16* __restrict__ Kswz, u16* __restrict__ Qswz,
                            u16* __restrict__ Vswz) {
  __shared__ __attribute__((aligned(16))) u16 Xs[32 * XSTR];      // f16 X tile [t][d]
  __shared__ __attribute__((aligned(16))) u16 Wt[DIM * XSTR];     // f16 W^T [e][d]
  __shared__ __attribute__((aligned(16))) u16 Qs[2][16 * XSTR];   // f16 Q rows (per Q-wave)
  const int tid = threadIdx.x;
  const int lane = tid & 63, w = tid >> 6, qd = lane >> 4, ln = lane & 15;
  const int b = blockIdx.y;
  const int tau = blockIdx.x;                 // global 32-row tile index, 0..127
  const long xbase = ((long)b * T_SEQ + tau * 32) * DIM;

  {
    // X tile: 32 rows x 64 cols, 8 f32 per thread
    const int r = tid >> 3, c0 = (tid & 7) * 8;
    float v[8];
    *(float4*)&v[0] = *(const float4*)(X + xbase + (long)r * DIM + c0);
    *(float4*)&v[4] = *(const float4*)(X + xbase + (long)r * DIM + c0 + 4);
    u16 h[8];
#pragma unroll
    for (int j = 0; j < 8; j++) h[j] = __builtin_bit_cast(u16, (f16)v[j]);
    *(uint4*)&Xs[r * XSTR + c0] = *(uint4*)&h[0];
    // W: 64x64, 16 f32 per thread, transposed scalar stores
    const int r2 = tid >> 2, c2 = (tid & 3) * 16;
    float wv[16];
#pragma unroll
    for (int i = 0; i < 4; i++)
      *(float4*)&wv[i * 4] = *(const float4*)(W + r2 * DIM + c2 + i * 4);
#pragma unroll
    for (int j = 0; j < 16; j++) Wt[(c2 + j) * XSTR + r2] = __builtin_bit_cast(u16, (f16)wv[j]);
  }
  __syncthreads();

  if (w == 0) {
    // K fragments, SLOT-PERMUTED: frag (tau, ct), lane ln reads tile-local row
    // krow = (ln>>2)*8 + ct*4 + (ln&3).
#pragma unroll
    for (int ct = 0; ct < 2; ct++) {
      const int krow = (ln >> 2) * 8 + ct * 4 + (ln & 3);
      const long F = ((long)b * 128 + tau) * 2 + ct;
#pragma unroll
      for (int ks = 0; ks < 2; ks++) {
        f16x8 kv = *(const f16x8*)&Xs[krow * XSTR + ks * 32 + qd * 8];
        *(f16x8*)(Kswz + (F * 2 + ks) * FRAG + lane * 8) = kv;
      }
    }
    // V d-block 0
    {
      const long Cb = (long)b * 4 + 0;
      bf16x8 vv;
#pragma unroll
      for (int j = 0; j < 8; j++) {
        f16 hv = __builtin_bit_cast(f16, Xs[(qd * 8 + j) * XSTR + 0 * 16 + ln]);
        vv[j] = (__bf16)(float)hv;
      }
      *(bf16x8*)(Vswz + (Cb * (T_SEQ / 32) + tau) * FRAG + lane * 8) = vv;
    }
  } else if (w == 1) {
    // V d-blocks 1..3
#pragma unroll
    for (int db = 1; db < 4; db++) {
      const long Cb = (long)b * 4 + db;
      bf16x8 vv;
#pragma unroll
      for (int j = 0; j < 8; j++) {
        f16 hv = __builtin_bit_cast(f16, Xs[(qd * 8 + j) * XSTR + db * 16 + ln]);
        vv[j] = (__bf16)(float)hv;
      }
      *(bf16x8*)(Vswz + (Cb * (T_SEQ / 32) + tau) * FRAG + lane * 8) = vv;
    }
  } else {
    // Q rows (w-2)*16 .. +16: X@W via MFMA, scale by log2e, emit A-fragments
    const int h2 = w - 2;             // 0..1
    const int rq = h2 * 16;
    floatx4 acc[4];
#pragma unroll
    for (int ct = 0; ct < 4; ct++) acc[ct] = (floatx4)0.0f;
#pragma unroll
    for (int ks = 0; ks < 2; ks++) {
      f16x8 aX = *(const f16x8*)&Xs[(rq + ln) * XSTR + ks * 32 + qd * 8];
#pragma unroll
      for (int ct = 0; ct < 4; ct++) {
        f16x8 bW = *(const f16x8*)&Wt[(ct * 16 + ln) * XSTR + ks * 32 + qd * 8];
        acc[ct] = __builtin_amdgcn_mfma_f32_16x16x32_f16(aX, bW, acc[ct], 0, 0, 0);
      }
    }
#pragma unroll
    for (int ct = 0; ct < 4; ct++)
#pragma unroll
      for (int r = 0; r < 4; r++)
        Qs[h2][(qd * 4 + r) * XSTR + ct * 16 + ln] =
            __builtin_bit_cast(u16, (f16)(acc[ct][r] * LOG2E));
    // wave-local rows: no barrier needed
    const long R = (long)b * (T_SEQ / 16) + tau * 2 + h2;
#pragma unroll
    for (int ks = 0; ks < 2; ks++) {
      f16x8 qv = *(const f16x8*)&Qs[h2][ln * XSTR + ks * 32 + qd * 8];
      *(f16x8*)(Qswz + (R * 2 + ks) * FRAG + lane * 8) = qv;
    }
  }
}

// ---- main, ROUND 12: r11's 2-tiles-per-barrier, with r11's two bugs fixed:
//  (1) __launch_bounds__(512, 2): hipcc's 2nd arg behaves CUDA-style
//      (blocks/CU): N=4 imposed a 64-VGPR cap -> r7/r11 spilled. N=2 ->
//      128-VGPR cap; LDS (66 KB) and grid (512 blocks) limit us to 2
//      blocks/CU regardless, so nothing is lost.
//  (2) V loads issued BEFORE the stage pair: waiting for bV (oldest) leaves
//      the stage loads in flight across both tiles (r11 had stage first, so
//      the bV wait forced vmcnt(0) and serialized the prefetch).
// One barrier + one stage burst per 256 keys; QK(t+1) MFMA independent of
// exp(t) VALU -> pipe overlap inside the superblock. K in 4 x 16 KB LDS
// buffers (pair-flip); V direct from L2 (b==XCD affinity).
// Rule #20: all register-array indices compile-time.
__launch_bounds__(512, 2)
__global__ void attn_kernel(const u16* __restrict__ Kswz, const u16* __restrict__ Qswz,
                            const u16* __restrict__ Vswz, float* __restrict__ out) {
  // smem: 4 K buffers x 16 KB (pairs flip); epilogue Opart (34816 B) aliases
  __shared__ __attribute__((aligned(16))) char smem[65536];
  __shared__ float lpart[8][32];
  float* Opart = (float*)smem;

  const int tid = threadIdx.x;
  const int lane = tid & 63;
  const int w = tid >> 6;           // 0..7
  const int qd = lane >> 4;
  const int ln = lane & 15;
  const int wg = w >> 2;            // q-group
  const int wk = w & 3;             // key subgroup
  const int bid = blockIdx.x;
  const int b = bid & 7;            // batch == XCD for L2 affinity
  const int q0 = (bid >> 3) * QT;
  const long bbase = (long)b * T_SEQ * DIM;

  // Q B-fragments pinned: 32 rows x 64 d for this q-group
  f16x8 aQ[2][2];
#pragma unroll
  for (int rb = 0; rb < 2; rb++)
#pragma unroll
    for (int ks = 0; ks < 2; ks++)
      aQ[rb][ks] = *(const f16x8*)(Qswz +
          (((long)b * (T_SEQ / 16) + (q0 >> 4) + wg * 2 + rb) * 2 + ks) * FRAG + lane * 8);

  // K stage source: wave w stages bytes w*2048..+2048 of each 16 KB tile-group
  const char* gKw = (const char*)Kswz + (long)b * 524288 + (long)w * 2048 + lane * 16;
  // V direct source: frag (db, tile t*4+wk) at b*524288 + db*131072 + (t*4+wk)*1024
  const char* gV = (const char*)Vswz + (long)b * 524288 + (long)wk * 1024 + lane * 16;

#define STAGE(dst, t)                                                                   \
  do {                                                                                  \
    const char* g = gKw + (long)(t) * 16384;                                            \
    char* l = (dst) + w * 2048;                                                         \
    __builtin_amdgcn_global_load_lds((gvoid*)(g), (svoid*)(l), 16, 0, 0);               \
    __builtin_amdgcn_global_load_lds((gvoid*)(g + 1024), (svoid*)(l + 1024), 16, 0, 0); \
  } while (0)

#define LOADV(BV, tv)                                                                   \
  do {                                                                                  \
    _Pragma("unroll") for (int db = 0; db < 4; db++)                                    \
      BV[db] = *(const bf16x8*)(gV + (long)(tv) * 4096 + (long)db * 131072);            \
  } while (0)

// one 128-key tile: K ds_read from KBUF, QK, exp -> pk, PV with given bV set
#define TILE(KBUF, BV)                                                                  \
  do {                                                                                  \
    const char* Kb_ = (KBUF) + wk * 4096;                                               \
    f16x8 bK_[2][2];                                                                    \
    _Pragma("unroll") for (int ct = 0; ct < 2; ct++)                                    \
      _Pragma("unroll") for (int ks = 0; ks < 2; ks++)                                  \
        bK_[ct][ks] = *(const f16x8*)(Kb_ + (ct * 2 + ks) * 1024 + lane * 16);          \
    floatx4 St_[2][2];                                                                  \
    _Pragma("unroll") for (int ct = 0; ct < 2; ct++)                                    \
      _Pragma("unroll") for (int rb = 0; rb < 2; rb++) St_[ct][rb] = (floatx4)0.0f;     \
    __builtin_amdgcn_s_setprio(1);                                                      \
    _Pragma("unroll") for (int ks = 0; ks < 2; ks++)                                    \
      _Pragma("unroll") for (int ct = 0; ct < 2; ct++)                                  \
        _Pragma("unroll") for (int rb = 0; rb < 2; rb++)                                \
          St_[ct][rb] = __builtin_amdgcn_mfma_f32_16x16x32_f16(bK_[ct][ks], aQ[rb][ks], \
                                                               St_[ct][rb], 0, 0, 0);   \
    __builtin_amdgcn_s_setprio(0);                                                      \
    bf16x8 pk_[2];                                                                      \
    _Pragma("unroll") for (int rb = 0; rb < 2; rb++) {                                  \
      float ps = 0.f;                                                                   \
      _Pragma("unroll") for (int ct = 0; ct < 2; ct++)                                  \
        _Pragma("unroll") for (int r = 0; r < 4; r++) {                                 \
          float p = EXP2(St_[ct][rb][r]);                                               \
          ps += p;                                                                      \
          pk_[rb][ct * 4 + r] = (__bf16)p;                                              \
        }                                                                               \
      lacc[rb] += ps;                                                                   \
    }                                                                                   \
    __builtin_amdgcn_s_setprio(1);                                                      \
    _Pragma("unroll") for (int rb = 0; rb < 2; rb++)                                    \
      _Pragma("unroll") for (int db = 0; db < 4; db++)                                  \
        O[rb][db] = __builtin_amdgcn_mfma_f32_16x16x32_bf16(pk_[rb], BV[db],            \
                                                            O[rb][db], 0, 0, 0);        \
    __builtin_amdgcn_s_setprio(0);                                                      \
  } while (0)

  floatx4 O[2][4];                  // [q 16-block][d 16-block], 32q x 64d per wave
  float lacc[2] = {0.f, 0.f};
#pragma unroll
  for (int rb = 0; rb < 2; rb++)
#pragma unroll
    for (int db = 0; db < 4; db++) O[rb][db] = (floatx4)0.0f;

  // prologue: stage tiles 0,1 into buffers 0,1
  STAGE(smem, 0);
  STAGE(smem + 16384, 1);
  __syncthreads();

#pragma unroll 1
  for (int j = 0; j < NIT / 2; j++) {
    const int a = 2 * j;
    char* cur = smem + (j & 1) * 32768;
    char* nxt = smem + ((j & 1) ^ 1) * 32768;
    bf16x8 bV0[4], bV1[4];
    LOADV(bV0, a);                   // oldest in vmcnt queue
    LOADV(bV1, a + 1);
    if (j + 1 < NIT / 2) {           // stage loads are YOUNGEST: bV waits
      STAGE(nxt, a + 2);             // leave them in flight
      STAGE(nxt + 16384, a + 3);
    }
    TILE(cur, bV0);                  // waits oldest 4 (bV0) only
    TILE(cur + 16384, bV1);          // waits next 4 (bV1) only
    __syncthreads();                 // staged pair landed; cur pair reads done
  }

  // l partials: reduce across qd lanes; lpart[w][q-local 0..31]
#pragma unroll
  for (int rb = 0; rb < 2; rb++) {
    float v = lacc[rb];
    v += __shfl_xor(v, 16, 64);
    v += __shfl_xor(v, 32, 64);
    if (qd == 0) lpart[w][rb * 16 + ln] = v;
  }

  // epilogue: FULLY UNROLLED (rule #20: runtime rb would home O in scratch)
#pragma unroll
  for (int rb = 0; rb < 2; rb++) {
    __syncthreads();  // rb=0: lpart published + last K reads done; rb=1: prior reads done
#pragma unroll
    for (int db = 0; db < 4; db++)
#pragma unroll
      for (int r = 0; r < 4; r++)
        Opart[(w * 16 + qd * 4 + r) * 68 + db * 16 + ln] = O[rb][db][r];
    __syncthreads();
    const int wg2 = tid >> 8;         // 0..1
    const int q2 = (tid >> 4) & 15;   // 0..15
    const int d0 = (tid & 15) * 4;    // 0..60
    float4 s = *(const float4*)&Opart[((wg2 * 4 + 0) * 16 + q2) * 68 + d0];
    const float4 s1 = *(const float4*)&Opart[((wg2 * 4 + 1) * 16 + q2) * 68 + d0];
    const float4 s2 = *(const float4*)&Opart[((wg2 * 4 + 2) * 16 + q2) * 68 + d0];
    const float4 s3 = *(const float4*)&Opart[((wg2 * 4 + 3) * 16 + q2) * 68 + d0];
    float l = lpart[wg2 * 4 + 0][rb * 16 + q2] + lpart[wg2 * 4 + 1][rb * 16 + q2] +
              lpart[wg2 * 4 + 2][rb * 16 + q2] + lpart[wg2 * 4 + 3][rb * 16 + q2];
    const float inv = 1.0f / l;
    float4 o;
    o.x = (s.x + s1.x + s2.x + s3.x) * inv;
    o.y = (s.y + s1.y + s2.y + s3.y) * inv;
    o.z = (s.z + s1.z + s2.z + s3.z) * inv;
    o.w = (s.w + s1.w + s2.w + s3.w) * inv;
    *(float4*)(out + bbase + (long)(q0 + wg2 * 32 + rb * 16 + q2) * DIM + d0) = o;
  }
#undef TILE
#undef LOADV
#undef STAGE
}

extern "C" void kernel_launch(void* const* d_in, const int* in_sizes, int n_in,
                              void* d_out, int out_size, void* d_ws, size_t ws_size,
                              hipStream_t stream) {
  const float* X = (const float*)d_in[0];
  const float* W = (const float*)d_in[1];
  float* out = (float*)d_out;
  const size_t SZ = (size_t)B_N * T_SEQ * DIM * 2;  // 4 MB per u16 array
  u16* Kswz = (u16*)d_ws;
  u16* Qswz = (u16*)((char*)d_ws + SZ);
  u16* Vswz = (u16*)((char*)d_ws + 2 * SZ);
  prep_kernel<<<dim3(T_SEQ / 32, B_N), 256, 0, stream>>>(X, W, Kswz, Qswz, Vswz);
  attn_kernel<<<dim3(B_N * (T_SEQ / QT)), 512, 0, stream>>>(Kswz, Qswz, Vswz, out);
}

// Round 14
// 113.019 us; speedup vs baseline: 1.2937x; 1.0055x over previous
//
#include <hip/hip_runtime.h>

typedef _Float16 f16;
typedef _Float16 f16x8 __attribute__((ext_vector_type(8)));
typedef __bf16 bf16x8 __attribute__((ext_vector_type(8)));
typedef float floatx4 __attribute__((ext_vector_type(4)));
typedef unsigned short u16;

#define B_N   8
#define T_SEQ 4096
#define DIM   64
#define QT    64     // q rows per attn block
#define XSTR  72     // prep LDS row stride in u16
#define LOG2E 1.44269504f
#define FRAG  512    // fragment = 512 u16 (1 KB): lane holds its 8 u16 at lane*8

#if __has_builtin(__builtin_amdgcn_exp2f)
#define EXP2(x) __builtin_amdgcn_exp2f(x)
#else
#define EXP2(x) exp2f(x)
#endif

typedef __attribute__((address_space(1))) const void gvoid;
typedef __attribute__((address_space(3))) void svoid;

// ---- prep v2: 32-row blocks, wave-specialized roles. Unchanged from round 6. ----
__launch_bounds__(256, 4)
__global__ void prep_kernel(const float* __restrict__ X, const float* __restrict__ W,
                            u16* __restrict__ Kswz, u16* __restrict__ Qswz,
                            u16* __restrict__ Vswz) {
  __shared__ __attribute__((aligned(16))) u16 Xs[32 * XSTR];      // f16 X tile [t][d]
  __shared__ __attribute__((aligned(16))) u16 Wt[DIM * XSTR];     // f16 W^T [e][d]
  __shared__ __attribute__((aligned(16))) u16 Qs[2][16 * XSTR];   // f16 Q rows (per Q-wave)
  const int tid = threadIdx.x;
  const int lane = tid & 63, w = tid >> 6, qd = lane >> 4, ln = lane & 15;
  const int b = blockIdx.y;
  const int tau = blockIdx.x;                 // global 32-row tile index, 0..127
  const long xbase = ((long)b * T_SEQ + tau * 32) * DIM;

  {
    // X tile: 32 rows x 64 cols, 8 f32 per thread
    const int r = tid >> 3, c0 = (tid & 7) * 8;
    float v[8];
    *(float4*)&v[0] = *(const float4*)(X + xbase + (long)r * DIM + c0);
    *(float4*)&v[4] = *(const float4*)(X + xbase + (long)r * DIM + c0 + 4);
    u16 h[8];
#pragma unroll
    for (int j = 0; j < 8; j++) h[j] = __builtin_bit_cast(u16, (f16)v[j]);
    *(uint4*)&Xs[r * XSTR + c0] = *(uint4*)&h[0];
    // W: 64x64, 16 f32 per thread, transposed scalar stores
    const int r2 = tid >> 2, c2 = (tid & 3) * 16;
    float wv[16];
#pragma unroll
    for (int i = 0; i < 4; i++)
      *(float4*)&wv[i * 4] = *(const float4*)(W + r2 * DIM + c2 + i * 4);
#pragma unroll
    for (int j = 0; j < 16; j++) Wt[(c2 + j) * XSTR + r2] = __builtin_bit_cast(u16, (f16)wv[j]);
  }
  __syncthreads();

  if (w == 0) {
    // K fragments, SLOT-PERMUTED: frag (tau, ct), lane ln reads tile-local row
    // krow = (ln>>2)*8 + ct*4 + (ln&3).
#pragma unroll
    for (int ct = 0; ct < 2; ct++) {
      const int krow = (ln >> 2) * 8 + ct * 4 + (ln & 3);
      const long F = ((long)b * 128 + tau) * 2 + ct;
#pragma unroll
      for (int ks = 0; ks < 2; ks++) {
        f16x8 kv = *(const f16x8*)&Xs[krow * XSTR + ks * 32 + qd * 8];
        *(f16x8*)(Kswz + (F * 2 + ks) * FRAG + lane * 8) = kv;
      }
    }
    // V d-block 0
    {
      const long Cb = (long)b * 4 + 0;
      bf16x8 vv;
#pragma unroll
      for (int j = 0; j < 8; j++) {
        f16 hv = __builtin_bit_cast(f16, Xs[(qd * 8 + j) * XSTR + 0 * 16 + ln]);
        vv[j] = (__bf16)(float)hv;
      }
      *(bf16x8*)(Vswz + (Cb * (T_SEQ / 32) + tau) * FRAG + lane * 8) = vv;
    }
  } else if (w == 1) {
    // V d-blocks 1..3
#pragma unroll
    for (int db = 1; db < 4; db++) {
      const long Cb = (long)b * 4 + db;
      bf16x8 vv;
#pragma unroll
      for (int j = 0; j < 8; j++) {
        f16 hv = __builtin_bit_cast(f16, Xs[(qd * 8 + j) * XSTR + db * 16 + ln]);
        vv[j] = (__bf16)(float)hv;
      }
      *(bf16x8*)(Vswz + (Cb * (T_SEQ / 32) + tau) * FRAG + lane * 8) = vv;
    }
  } else {
    // Q rows (w-2)*16 .. +16: X@W via MFMA, scale by log2e, emit A-fragments
    const int h2 = w - 2;             // 0..1
    const int rq = h2 * 16;
    floatx4 acc[4];
#pragma unroll
    for (int ct = 0; ct < 4; ct++) acc[ct] = (floatx4)0.0f;
#pragma unroll
    for (int ks = 0; ks < 2; ks++) {
      f16x8 aX = *(const f16x8*)&Xs[(rq + ln) * XSTR + ks * 32 + qd * 8];
#pragma unroll
      for (int ct = 0; ct < 4; ct++) {
        f16x8 bW = *(const f16x8*)&Wt[(ct * 16 + ln) * XSTR + ks * 32 + qd * 8];
        acc[ct] = __builtin_amdgcn_mfma_f32_16x16x32_f16(aX, bW, acc[ct], 0, 0, 0);
      }
    }
#pragma unroll
    for (int ct = 0; ct < 4; ct++)
#pragma unroll
      for (int r = 0; r < 4; r++)
        Qs[h2][(qd * 4 + r) * XSTR + ct * 16 + ln] =
            __builtin_bit_cast(u16, (f16)(acc[ct][r] * LOG2E));
    // wave-local rows: no barrier needed
    const long R = (long)b * (T_SEQ / 16) + tau * 2 + h2;
#pragma unroll
    for (int ks = 0; ks < 2; ks++) {
      f16x8 qv = *(const f16x8*)&Qs[h2][ln * XSTR + ks * 32 + qd * 8];
      *(f16x8*)(Qswz + (R * 2 + ks) * FRAG + lane * 8) = qv;
    }
  }
}

// ---- main, ROUND 13 (resubmitted unchanged after infra failure): r9 inner
// loop VERBATIM (best: 46.2 us), split-K. Ledger: 2-tiles/barrier lost (r12,
// clean), pipelining lost (r7/r8), smaller q-tiles lost (r10). Untested clean
// lever: more independent blocks per CU at CONSTANT per-wave efficiency.
// SPLIT=1: grid 1024 (4 blocks/CU, LDS 36 KB fits exactly 4), each block does
// half the keys (NIT 16), writes f32 partial O + partial l; reduce_kernel
// combines. Per-wave per-iter work, VGPR (52), and aggregate L2 traffic
// identical to r9 — only block-level parallelism doubles. SPLIT=0 is the r9
// fallback if ws too small. Rule #20: all reg-array indices compile-time.
template <int SPLIT>
__launch_bounds__(512, 4)
__global__ void attn_kernel(const u16* __restrict__ Kswz, const u16* __restrict__ Qswz,
                            const u16* __restrict__ Vswz, float* __restrict__ out,
                            float* __restrict__ Op, float* __restrict__ Lp) {
  // smem: K dbuf 2 x 16 KB during main loop; epilogue Opart (34816 B) aliases
  __shared__ __attribute__((aligned(16))) char smem[35840];
  __shared__ float lpart[8][32];
  float* Opart = (float*)smem;

  const int tid = threadIdx.x;
  const int lane = tid & 63;
  const int w = tid >> 6;           // 0..7
  const int qd = lane >> 4;
  const int ln = lane & 15;
  const int wg = w >> 2;            // q-group
  const int wk = w & 3;             // key subgroup
  const int bid = blockIdx.x;
  const int b = bid & 7;            // batch == XCD for L2 affinity
  const int h = SPLIT ? ((bid >> 3) & 1) : 0;   // key half
  const int g = SPLIT ? (bid >> 4) : (bid >> 3);
  const int q0 = g * QT;
  const int NITL = SPLIT ? 16 : 32;
  const long bbase = (long)b * T_SEQ * DIM;

  // Q B-fragments pinned: 32 rows x 64 d for this q-group
  f16x8 aQ[2][2];
#pragma unroll
  for (int rb = 0; rb < 2; rb++)
#pragma unroll
    for (int ks = 0; ks < 2; ks++)
      aQ[rb][ks] = *(const f16x8*)(Qswz +
          (((long)b * (T_SEQ / 16) + (q0 >> 4) + wg * 2 + rb) * 2 + ks) * FRAG + lane * 8);

  // K stage source: wave w stages frags w*2, w*2+1 of the 16 per tile-group;
  // key-half offset = h*64 tau-tiles = h*262144 bytes
  const char* gKw = (const char*)Kswz + (long)b * 524288 + (long)h * 262144 +
                    (long)w * 2048 + lane * 16;
  // V direct: frag (db, tau) at b*524288 + db*131072 + tau*1024; tau0 = h*64
  const char* gV = (const char*)Vswz + (long)b * 524288 + (long)h * 65536 +
                   (long)wk * 1024 + lane * 16;

#define STAGE(bufv, t)                                                                  \
  do {                                                                                  \
    const char* g_ = gKw + (long)(t) * 16384;                                           \
    char* l_ = smem + (bufv) * 16384 + w * 2048;                                        \
    __builtin_amdgcn_global_load_lds((gvoid*)(g_), (svoid*)(l_), 16, 0, 0);             \
    __builtin_amdgcn_global_load_lds((gvoid*)(g_ + 1024), (svoid*)(l_ + 1024), 16, 0, 0); \
  } while (0)

  floatx4 O[2][4];                  // [q 16-block][d 16-block], 32q x 64d per wave
  float lacc[2] = {0.f, 0.f};
#pragma unroll
  for (int rb = 0; rb < 2; rb++)
#pragma unroll
    for (int db = 0; db < 4; db++) O[rb][db] = (floatx4)0.0f;

  STAGE(0, 0);
  __syncthreads();

  int buf = 0;
#pragma unroll 1
  for (int t = 0; t < NITL; t++) {
    // V fragments: global loads FIRST (oldest in vmcnt queue -> PV's wait
    // leaves the younger stage loads outstanding)
    bf16x8 bV[4];
#pragma unroll
    for (int db = 0; db < 4; db++)
      bV[db] = *(const bf16x8*)(gV + (long)t * 4096 + (long)db * 131072);

    // prefetch next K tile-group into the other buffer (async)
    if (t + 1 < NITL) STAGE(buf ^ 1, t + 1);

    // K LDS -> registers (linear 1 KB fragments: conflict-free b128 reads)
    const char* Kb = smem + buf * 16384 + wk * 4096;
    f16x8 bK[2][2];
#pragma unroll
    for (int ct = 0; ct < 2; ct++)
#pragma unroll
      for (int ks = 0; ks < 2; ks++)
        bK[ct][ks] = *(const f16x8*)(Kb + (ct * 2 + ks) * 1024 + lane * 16);

    // QK^T: S^T[32k x 32q]
    floatx4 St[2][2];
#pragma unroll
    for (int ct = 0; ct < 2; ct++)
#pragma unroll
      for (int rb = 0; rb < 2; rb++) St[ct][rb] = (floatx4)0.0f;
    __builtin_amdgcn_s_setprio(1);
#pragma unroll
    for (int ks = 0; ks < 2; ks++)
#pragma unroll
      for (int ct = 0; ct < 2; ct++)
#pragma unroll
        for (int rb = 0; rb < 2; rb++)
          St[ct][rb] = __builtin_amdgcn_mfma_f32_16x16x32_f16(bK[ct][ks], aQ[rb][ks], St[ct][rb], 0, 0, 0);
    __builtin_amdgcn_s_setprio(0);

    // P = 2^S' in registers: slot (ct,qd,r) -> A-frag element j = ct*4 + r
    bf16x8 pk[2];
#pragma unroll
    for (int rb = 0; rb < 2; rb++) {
      float ps = 0.f;
#pragma unroll
      for (int ct = 0; ct < 2; ct++)
#pragma unroll
        for (int r = 0; r < 4; r++) {
          float p = EXP2(St[ct][rb][r]);
          ps += p;
          pk[rb][ct * 4 + r] = (__bf16)p;
        }
      lacc[rb] += ps;
    }

    // PV: O[32q x 64d] += P[32q x 32k] V[32k x 64d]
    __builtin_amdgcn_s_setprio(1);
#pragma unroll
    for (int rb = 0; rb < 2; rb++)
#pragma unroll
      for (int db = 0; db < 4; db++)
        O[rb][db] = __builtin_amdgcn_mfma_f32_16x16x32_bf16(pk[rb], bV[db], O[rb][db], 0, 0, 0);
    __builtin_amdgcn_s_setprio(0);

    __syncthreads();  // drains vmcnt (next K tile staged) + lgkm; publishes buf^1
    buf ^= 1;
  }

  // l partials: reduce across qd lanes; lpart[w][q-local 0..31]
#pragma unroll
  for (int rb = 0; rb < 2; rb++) {
    float v = lacc[rb];
    v += __shfl_xor(v, 16, 64);
    v += __shfl_xor(v, 32, 64);
    if (qd == 0) lpart[w][rb * 16 + ln] = v;
  }

  // epilogue: FULLY UNROLLED (rule #20: runtime rb would home O in scratch)
#pragma unroll
  for (int rb = 0; rb < 2; rb++) {
    __syncthreads();  // rb=0: lpart published + last K reads done; rb=1: prior reads done
#pragma unroll
    for (int db = 0; db < 4; db++)
#pragma unroll
      for (int r = 0; r < 4; r++)
        Opart[(w * 16 + qd * 4 + r) * 68 + db * 16 + ln] = O[rb][db][r];
    __syncthreads();
    const int wg2 = tid >> 8;         // 0..1
    const int q2 = (tid >> 4) & 15;   // 0..15
    const int d0 = (tid & 15) * 4;    // 0..60
    const int ql = wg2 * 32 + rb * 16 + q2;   // q-local 0..63
    float4 s = *(const float4*)&Opart[((wg2 * 4 + 0) * 16 + q2) * 68 + d0];
    const float4 s1 = *(const float4*)&Opart[((wg2 * 4 + 1) * 16 + q2) * 68 + d0];
    const float4 s2 = *(const float4*)&Opart[((wg2 * 4 + 2) * 16 + q2) * 68 + d0];
    const float4 s3 = *(const float4*)&Opart[((wg2 * 4 + 3) * 16 + q2) * 68 + d0];
    float l = lpart[wg2 * 4 + 0][rb * 16 + q2] + lpart[wg2 * 4 + 1][rb * 16 + q2] +
              lpart[wg2 * 4 + 2][rb * 16 + q2] + lpart[wg2 * 4 + 3][rb * 16 + q2];
    float4 o;
    o.x = s.x + s1.x + s2.x + s3.x;
    o.y = s.y + s1.y + s2.y + s3.y;
    o.z = s.z + s1.z + s2.z + s3.z;
    o.w = s.w + s1.w + s2.w + s3.w;
    if (SPLIT) {
      *(float4*)(Op + (long)bid * (QT * DIM) + ql * DIM + d0) = o;
      if (d0 == 0) Lp[(long)bid * QT + ql] = l;
    } else {
      const float inv = 1.0f / l;
      o.x *= inv; o.y *= inv; o.z *= inv; o.w *= inv;
      *(float4*)(out + bbase + (long)(q0 + ql) * DIM + d0) = o;
    }
  }
#undef STAGE
}

// combine the two key-halves: out = (Op0+Op1)/(l0+l1). 512 blocks (b,g).
__launch_bounds__(256, 8)
__global__ void reduce_kernel(const float* __restrict__ Op, const float* __restrict__ Lp,
                              float* __restrict__ out) {
  const int rb = blockIdx.x;          // 0..511
  const int b = rb & 7, g = rb >> 3;
  const int bid0 = g * 16 + b;        // half 0 block id
  const int bid1 = g * 16 + 8 + b;    // half 1 block id
  const long p0 = (long)bid0 * (QT * DIM);
  const long p1 = (long)bid1 * (QT * DIM);
  const long obase = ((long)b * T_SEQ + (long)g * QT) * DIM;
#pragma unroll
  for (int i = 0; i < 4; i++) {
    const int lin4 = i * 256 + threadIdx.x;   // float4 index, 0..1023
    const int q = lin4 >> 4;
    const int d0 = (lin4 & 15) * 4;
    float4 a = *(const float4*)(Op + p0 + (long)lin4 * 4);
    float4 c = *(const float4*)(Op + p1 + (long)lin4 * 4);
    const float inv = 1.0f / (Lp[(long)bid0 * QT + q] + Lp[(long)bid1 * QT + q]);
    float4 o;
    o.x = (a.x + c.x) * inv;
    o.y = (a.y + c.y) * inv;
    o.z = (a.z + c.z) * inv;
    o.w = (a.w + c.w) * inv;
    *(float4*)(out + obase + (long)q * DIM + d0) = o;
  }
}

extern "C" void kernel_launch(void* const* d_in, const int* in_sizes, int n_in,
                              void* d_out, int out_size, void* d_ws, size_t ws_size,
                              hipStream_t stream) {
  const float* X = (const float*)d_in[0];
  const float* W = (const float*)d_in[1];
  float* out = (float*)d_out;
  const size_t SZ = (size_t)B_N * T_SEQ * DIM * 2;      // 4 MB per u16 array
  const size_t OPSZ = (size_t)1024 * QT * DIM * 4;      // 16 MB f32 partial O
  const size_t LPSZ = (size_t)1024 * QT * 4;            // 256 KB partial l
  u16* Kswz = (u16*)d_ws;
  u16* Qswz = (u16*)((char*)d_ws + SZ);
  u16* Vswz = (u16*)((char*)d_ws + 2 * SZ);
  float* Op = (float*)((char*)d_ws + 3 * SZ);
  float* Lp = (float*)((char*)d_ws + 3 * SZ + OPSZ);

  prep_kernel<<<dim3(T_SEQ / 32, B_N), 256, 0, stream>>>(X, W, Kswz, Qswz, Vswz);
  if (ws_size >= 3 * SZ + OPSZ + LPSZ) {
    attn_kernel<1><<<dim3(B_N * (T_SEQ / QT) * 2), 512, 0, stream>>>(
        Kswz, Qswz, Vswz, out, Op, Lp);
    reduce_kernel<<<dim3(B_N * (T_SEQ / QT)), 256, 0, stream>>>(Op, Lp, out);
  } else {
    attn_kernel<0><<<dim3(B_N * (T_SEQ / QT)), 512, 0, stream>>>(
        Kswz, Qswz, Vswz, out, Op, Lp);
  }
}

// Round 15
// 112.685 us; speedup vs baseline: 1.2975x; 1.0030x over previous
//
#include <hip/hip_runtime.h>

typedef _Float16 f16;
typedef _Float16 f16x8 __attribute__((ext_vector_type(8)));
typedef __bf16 bf16x8 __attribute__((ext_vector_type(8)));
typedef float floatx4 __attribute__((ext_vector_type(4)));
typedef unsigned short u16;

#define B_N   8
#define T_SEQ 4096
#define DIM   64
#define QT    64     // q rows per attn block
#define NIT   32     // 32 tiles of 128 keys (32/wave x 4 key-subgroups)
#define XSTR  72     // prep LDS row stride in u16
#define LOG2E 1.44269504f
#define FRAG  512    // fragment = 512 u16 (1 KB): lane holds its 8 u16 at lane*8

#if __has_builtin(__builtin_amdgcn_exp2f)
#define EXP2(x) __builtin_amdgcn_exp2f(x)
#else
#define EXP2(x) exp2f(x)
#endif

typedef __attribute__((address_space(1))) const void gvoid;
typedef __attribute__((address_space(3))) void svoid;

// ---- prep v2: 32-row blocks, wave-specialized roles. Unchanged from round 6. ----
__launch_bounds__(256, 4)
__global__ void prep_kernel(const float* __restrict__ X, const float* __restrict__ W,
                            u16* __restrict__ Kswz, u16* __restrict__ Qswz,
                            u16* __restrict__ Vswz) {
  __shared__ __attribute__((aligned(16))) u16 Xs[32 * XSTR];      // f16 X tile [t][d]
  __shared__ __attribute__((aligned(16))) u16 Wt[DIM * XSTR];     // f16 W^T [e][d]
  __shared__ __attribute__((aligned(16))) u16 Qs[2][16 * XSTR];   // f16 Q rows (per Q-wave)
  const int tid = threadIdx.x;
  const int lane = tid & 63, w = tid >> 6, qd = lane >> 4, ln = lane & 15;
  const int b = blockIdx.y;
  const int tau = blockIdx.x;                 // global 32-row tile index, 0..127
  const long xbase = ((long)b * T_SEQ + tau * 32) * DIM;

  {
    // X tile: 32 rows x 64 cols, 8 f32 per thread
    const int r = tid >> 3, c0 = (tid & 7) * 8;
    float v[8];
    *(float4*)&v[0] = *(const float4*)(X + xbase + (long)r * DIM + c0);
    *(float4*)&v[4] = *(const float4*)(X + xbase + (long)r * DIM + c0 + 4);
    u16 h[8];
#pragma unroll
    for (int j = 0; j < 8; j++) h[j] = __builtin_bit_cast(u16, (f16)v[j]);
    *(uint4*)&Xs[r * XSTR + c0] = *(uint4*)&h[0];
    // W: 64x64, 16 f32 per thread, transposed scalar stores
    const int r2 = tid >> 2, c2 = (tid & 3) * 16;
    float wv[16];
#pragma unroll
    for (int i = 0; i < 4; i++)
      *(float4*)&wv[i * 4] = *(const float4*)(W + r2 * DIM + c2 + i * 4);
#pragma unroll
    for (int j = 0; j < 16; j++) Wt[(c2 + j) * XSTR + r2] = __builtin_bit_cast(u16, (f16)wv[j]);
  }
  __syncthreads();

  if (w == 0) {
    // K fragments, SLOT-PERMUTED: frag (tau, ct), lane ln reads tile-local row
    // krow = (ln>>2)*8 + ct*4 + (ln&3).
#pragma unroll
    for (int ct = 0; ct < 2; ct++) {
      const int krow = (ln >> 2) * 8 + ct * 4 + (ln & 3);
      const long F = ((long)b * 128 + tau) * 2 + ct;
#pragma unroll
      for (int ks = 0; ks < 2; ks++) {
        f16x8 kv = *(const f16x8*)&Xs[krow * XSTR + ks * 32 + qd * 8];
        *(f16x8*)(Kswz + (F * 2 + ks) * FRAG + lane * 8) = kv;
      }
    }
    // V d-block 0
    {
      const long Cb = (long)b * 4 + 0;
      bf16x8 vv;
#pragma unroll
      for (int j = 0; j < 8; j++) {
        f16 hv = __builtin_bit_cast(f16, Xs[(qd * 8 + j) * XSTR + 0 * 16 + ln]);
        vv[j] = (__bf16)(float)hv;
      }
      *(bf16x8*)(Vswz + (Cb * (T_SEQ / 32) + tau) * FRAG + lane * 8) = vv;
    }
  } else if (w == 1) {
    // V d-blocks 1..3
#pragma unroll
    for (int db = 1; db < 4; db++) {
      const long Cb = (long)b * 4 + db;
      bf16x8 vv;
#pragma unroll
      for (int j = 0; j < 8; j++) {
        f16 hv = __builtin_bit_cast(f16, Xs[(qd * 8 + j) * XSTR + db * 16 + ln]);
        vv[j] = (__bf16)(float)hv;
      }
      *(bf16x8*)(Vswz + (Cb * (T_SEQ / 32) + tau) * FRAG + lane * 8) = vv;
    }
  } else {
    // Q rows (w-2)*16 .. +16: X@W via MFMA, scale by log2e, emit A-fragments
    const int h2 = w - 2;             // 0..1
    const int rq = h2 * 16;
    floatx4 acc[4];
#pragma unroll
    for (int ct = 0; ct < 4; ct++) acc[ct] = (floatx4)0.0f;
#pragma unroll
    for (int ks = 0; ks < 2; ks++) {
      f16x8 aX = *(const f16x8*)&Xs[(rq + ln) * XSTR + ks * 32 + qd * 8];
#pragma unroll
      for (int ct = 0; ct < 4; ct++) {
        f16x8 bW = *(const f16x8*)&Wt[(ct * 16 + ln) * XSTR + ks * 32 + qd * 8];
        acc[ct] = __builtin_amdgcn_mfma_f32_16x16x32_f16(aX, bW, acc[ct], 0, 0, 0);
      }
    }
#pragma unroll
    for (int ct = 0; ct < 4; ct++)
#pragma unroll
      for (int r = 0; r < 4; r++)
        Qs[h2][(qd * 4 + r) * XSTR + ct * 16 + ln] =
            __builtin_bit_cast(u16, (f16)(acc[ct][r] * LOG2E));
    // wave-local rows: no barrier needed
    const long R = (long)b * (T_SEQ / 16) + tau * 2 + h2;
#pragma unroll
    for (int ks = 0; ks < 2; ks++) {
      f16x8 qv = *(const f16x8*)&Qs[h2][ln * XSTR + ks * 32 + qd * 8];
      *(f16x8*)(Qswz + (R * 2 + ks) * FRAG + lane * 8) = qv;
    }
  }
}

// ---- main, ROUND 15: BARRIER-FREE main loop. r14 proved the limiter is
// neither occupancy (2x blocks -> identical throughput, identical pipe %),
// nor barrier count (r12), nor per-wave overhead (r10): every variant shares
// the per-iter __syncthreads that phase-aligns all waves. Here each wave
// stages ITS OWN 4 KB K tile into a PRIVATE LDS slot (global_load_lds) and
// waits on its own counted vmcnt — producer==consumer, so NO barrier is
// needed in the main loop. Waves free-run and slip to fill each other's
// dependency bubbles (counted-vmcnt T4 pattern, never vmcnt(0) in-loop).
// Cost: 2x K stage traffic (L2-absorbed) + 64 KB LDS (still 2 blocks/CU).
// vmcnt arithmetic: per iter issue V(t) x4 (oldest), stage(t+1) x4
// (youngest). Before ds_read K(t): stage(t) has exactly 8 younger ops ->
// s_waitcnt vmcnt(8). PV's bV wait is compiler-inserted vmcnt(4) (stage
// loads remain in flight). V direct from L2 (b==XCD). Epilogue keeps its
// barriers (cross-wave Opart). Rule #20: all reg indices compile-time.
__launch_bounds__(512, 2)
__global__ void attn_kernel(const u16* __restrict__ Kswz, const u16* __restrict__ Qswz,
                            const u16* __restrict__ Vswz, float* __restrict__ out) {
  // smem: 8 waves x 2 bufs x 4 KB private K slots = 64 KB; epilogue Opart
  // (34816 B) aliases. lpart separate.
  __shared__ __attribute__((aligned(16))) char smem[65536];
  __shared__ float lpart[8][32];
  float* Opart = (float*)smem;

  const int tid = threadIdx.x;
  const int lane = tid & 63;
  const int w = tid >> 6;           // 0..7
  const int qd = lane >> 4;
  const int ln = lane & 15;
  const int wg = w >> 2;            // q-group
  const int wk = w & 3;             // key subgroup
  const int bid = blockIdx.x;
  const int b = bid & 7;            // batch == XCD for L2 affinity
  const int q0 = (bid >> 3) * QT;
  const long bbase = (long)b * T_SEQ * DIM;

  // Q B-fragments pinned: 32 rows x 64 d for this q-group
  f16x8 aQ[2][2];
#pragma unroll
  for (int rb = 0; rb < 2; rb++)
#pragma unroll
    for (int ks = 0; ks < 2; ks++)
      aQ[rb][ks] = *(const f16x8*)(Qswz +
          (((long)b * (T_SEQ / 16) + (q0 >> 4) + wg * 2 + rb) * 2 + ks) * FRAG + lane * 8);

  // per-wave K stage source: tile for iter t is (t*4 + wk), 4 KB at
  // b*524288 + (t*4+wk)*4096
  const char* gK = (const char*)Kswz + (long)b * 524288 + (long)wk * 4096 + lane * 16;
  // V direct: frag (db, tile t*4+wk) at b*524288 + db*131072 + (t*4+wk)*1024
  const char* gV = (const char*)Vswz + (long)b * 524288 + (long)wk * 1024 + lane * 16;

#define STAGE(bufv, t)                                                                  \
  do {                                                                                  \
    const char* g_ = gK + (long)(t) * 16384;                                            \
    char* l_ = smem + w * 8192 + (bufv) * 4096;                                         \
    __builtin_amdgcn_global_load_lds((gvoid*)(g_), (svoid*)(l_), 16, 0, 0);             \
    __builtin_amdgcn_global_load_lds((gvoid*)(g_ + 1024), (svoid*)(l_ + 1024), 16, 0, 0); \
    __builtin_amdgcn_global_load_lds((gvoid*)(g_ + 2048), (svoid*)(l_ + 2048), 16, 0, 0); \
    __builtin_amdgcn_global_load_lds((gvoid*)(g_ + 3072), (svoid*)(l_ + 3072), 16, 0, 0); \
  } while (0)

  floatx4 O[2][4];                  // [q 16-block][d 16-block], 32q x 64d per wave
  float lacc[2] = {0.f, 0.f};
#pragma unroll
  for (int rb = 0; rb < 2; rb++)
#pragma unroll
    for (int db = 0; db < 4; db++) O[rb][db] = (floatx4)0.0f;

  STAGE(0, 0);                      // 4 outstanding = loop-top invariant

  int buf = 0;
#pragma unroll 1
  for (int t = 0; t < NIT; t++) {
    // V fragments: issued first (older than stage loads)
    bf16x8 bV[4];
#pragma unroll
    for (int db = 0; db < 4; db++)
      bV[db] = *(const bf16x8*)(gV + (long)t * 4096 + (long)db * 131072);
    asm volatile("" ::: "memory");  // pin V issue before stage issue

    // stage next tile into my other slot ((t+1)&31 wraps harmlessly at t=31;
    // the epilogue barrier drains it)
    STAGE(buf ^ 1, (t + 1) & 31);

    // my stage(t) landed when <=8 ops outstanding (4 V + 4 stage(t+1))
    asm volatile("s_waitcnt vmcnt(8)" ::: "memory");

    // K LDS -> registers from MY slot (linear 1 KB frags, conflict-free b128)
    const char* Kb = smem + w * 8192 + buf * 4096;
    f16x8 bK[2][2];
#pragma unroll
    for (int ct = 0; ct < 2; ct++)
#pragma unroll
      for (int ks = 0; ks < 2; ks++)
        bK[ct][ks] = *(const f16x8*)(Kb + (ct * 2 + ks) * 1024 + lane * 16);

    // QK^T: S^T[32k x 32q]
    floatx4 St[2][2];
#pragma unroll
    for (int ct = 0; ct < 2; ct++)
#pragma unroll
      for (int rb = 0; rb < 2; rb++) St[ct][rb] = (floatx4)0.0f;
    __builtin_amdgcn_s_setprio(1);
#pragma unroll
    for (int ks = 0; ks < 2; ks++)
#pragma unroll
      for (int ct = 0; ct < 2; ct++)
#pragma unroll
        for (int rb = 0; rb < 2; rb++)
          St[ct][rb] = __builtin_amdgcn_mfma_f32_16x16x32_f16(bK[ct][ks], aQ[rb][ks], St[ct][rb], 0, 0, 0);
    __builtin_amdgcn_s_setprio(0);

    // P = 2^S' in registers: slot (ct,qd,r) -> A-frag element j = ct*4 + r
    bf16x8 pk[2];
#pragma unroll
    for (int rb = 0; rb < 2; rb++) {
      float ps = 0.f;
#pragma unroll
      for (int ct = 0; ct < 2; ct++)
#pragma unroll
        for (int r = 0; r < 4; r++) {
          float p = EXP2(St[ct][rb][r]);
          ps += p;
          pk[rb][ct * 4 + r] = (__bf16)p;
        }
      lacc[rb] += ps;
    }

    // PV: O += P V  (compiler inserts vmcnt(4) for bV — stage stays in flight)
    __builtin_amdgcn_s_setprio(1);
#pragma unroll
    for (int rb = 0; rb < 2; rb++)
#pragma unroll
      for (int db = 0; db < 4; db++)
        O[rb][db] = __builtin_amdgcn_mfma_f32_16x16x32_bf16(pk[rb], bV[db], O[rb][db], 0, 0, 0);
    __builtin_amdgcn_s_setprio(0);

    buf ^= 1;                       // NO barrier — waves free-run
  }

  // l partials: reduce across qd lanes; lpart[w][q-local 0..31]
#pragma unroll
  for (int rb = 0; rb < 2; rb++) {
    float v = lacc[rb];
    v += __shfl_xor(v, 16, 64);
    v += __shfl_xor(v, 32, 64);
    if (qd == 0) lpart[w][rb * 16 + ln] = v;
  }

  // epilogue: FULLY UNROLLED (rule #20); barriers here only. First
  // __syncthreads drains each wave's vmcnt (wrap-stage writes included).
#pragma unroll
  for (int rb = 0; rb < 2; rb++) {
    __syncthreads();  // rb=0: lpart published + all stage writes drained
#pragma unroll
    for (int db = 0; db < 4; db++)
#pragma unroll
      for (int r = 0; r < 4; r++)
        Opart[(w * 16 + qd * 4 + r) * 68 + db * 16 + ln] = O[rb][db][r];
    __syncthreads();
    const int wg2 = tid >> 8;         // 0..1
    const int q2 = (tid >> 4) & 15;   // 0..15
    const int d0 = (tid & 15) * 4;    // 0..60
    float4 s = *(const float4*)&Opart[((wg2 * 4 + 0) * 16 + q2) * 68 + d0];
    const float4 s1 = *(const float4*)&Opart[((wg2 * 4 + 1) * 16 + q2) * 68 + d0];
    const float4 s2 = *(const float4*)&Opart[((wg2 * 4 + 2) * 16 + q2) * 68 + d0];
    const float4 s3 = *(const float4*)&Opart[((wg2 * 4 + 3) * 16 + q2) * 68 + d0];
    float l = lpart[wg2 * 4 + 0][rb * 16 + q2] + lpart[wg2 * 4 + 1][rb * 16 + q2] +
              lpart[wg2 * 4 + 2][rb * 16 + q2] + lpart[wg2 * 4 + 3][rb * 16 + q2];
    const float inv = 1.0f / l;
    float4 o;
    o.x = (s.x + s1.x + s2.x + s3.x) * inv;
    o.y = (s.y + s1.y + s2.y + s3.y) * inv;
    o.z = (s.z + s1.z + s2.z + s3.z) * inv;
    o.w = (s.w + s1.w + s2.w + s3.w) * inv;
    *(float4*)(out + bbase + (long)(q0 + wg2 * 32 + rb * 16 + q2) * DIM + d0) = o;
  }
#undef STAGE
}

extern "C" void kernel_launch(void* const* d_in, const int* in_sizes, int n_in,
                              void* d_out, int out_size, void* d_ws, size_t ws_size,
                              hipStream_t stream) {
  const float* X = (const float*)d_in[0];
  const float* W = (const float*)d_in[1];
  float* out = (float*)d_out;
  const size_t SZ = (size_t)B_N * T_SEQ * DIM * 2;  // 4 MB per u16 array
  u16* Kswz = (u16*)d_ws;
  u16* Qswz = (u16*)((char*)d_ws + SZ);
  u16* Vswz = (u16*)((char*)d_ws + 2 * SZ);
  prep_kernel<<<dim3(T_SEQ / 32, B_N), 256, 0, stream>>>(X, W, Kswz, Qswz, Vswz);
  attn_kernel<<<dim3(B_N * (T_SEQ / QT)), 512, 0, stream>>>(Kswz, Qswz, Vswz, out);
}

// Round 16
// 105.312 us; speedup vs baseline: 1.3883x; 1.0700x over previous
//
#include <hip/hip_runtime.h>

typedef _Float16 f16;
typedef _Float16 f16x8 __attribute__((ext_vector_type(8)));
typedef __bf16 bf16x8 __attribute__((ext_vector_type(8)));
typedef float floatx4 __attribute__((ext_vector_type(4)));
typedef unsigned short u16;

#define B_N   8
#define T_SEQ 4096
#define DIM   64
#define QT    64     // q rows per attn block
#define NIT   32     // 32 tiles of 128 keys (32/wave x 4 key-subgroups)
#define XSTR  72     // prep LDS row stride in u16
#define LOG2E 1.44269504f
#define FRAG  512    // fragment = 512 u16 (1 KB): lane holds its 8 u16 at lane*8

#if __has_builtin(__builtin_amdgcn_exp2f)
#define EXP2(x) __builtin_amdgcn_exp2f(x)
#else
#define EXP2(x) exp2f(x)
#endif

typedef __attribute__((address_space(1))) const void gvoid;
typedef __attribute__((address_space(3))) void svoid;

// ---- prep v2: 32-row blocks, wave-specialized roles. Unchanged from round 6. ----
__launch_bounds__(256, 4)
__global__ void prep_kernel(const float* __restrict__ X, const float* __restrict__ W,
                            u16* __restrict__ Kswz, u16* __restrict__ Qswz,
                            u16* __restrict__ Vswz) {
  __shared__ __attribute__((aligned(16))) u16 Xs[32 * XSTR];      // f16 X tile [t][d]
  __shared__ __attribute__((aligned(16))) u16 Wt[DIM * XSTR];     // f16 W^T [e][d]
  __shared__ __attribute__((aligned(16))) u16 Qs[2][16 * XSTR];   // f16 Q rows (per Q-wave)
  const int tid = threadIdx.x;
  const int lane = tid & 63, w = tid >> 6, qd = lane >> 4, ln = lane & 15;
  const int b = blockIdx.y;
  const int tau = blockIdx.x;                 // global 32-row tile index, 0..127
  const long xbase = ((long)b * T_SEQ + tau * 32) * DIM;

  {
    // X tile: 32 rows x 64 cols, 8 f32 per thread
    const int r = tid >> 3, c0 = (tid & 7) * 8;
    float v[8];
    *(float4*)&v[0] = *(const float4*)(X + xbase + (long)r * DIM + c0);
    *(float4*)&v[4] = *(const float4*)(X + xbase + (long)r * DIM + c0 + 4);
    u16 h[8];
#pragma unroll
    for (int j = 0; j < 8; j++) h[j] = __builtin_bit_cast(u16, (f16)v[j]);
    *(uint4*)&Xs[r * XSTR + c0] = *(uint4*)&h[0];
    // W: 64x64, 16 f32 per thread, transposed scalar stores
    const int r2 = tid >> 2, c2 = (tid & 3) * 16;
    float wv[16];
#pragma unroll
    for (int i = 0; i < 4; i++)
      *(float4*)&wv[i * 4] = *(const float4*)(W + r2 * DIM + c2 + i * 4);
#pragma unroll
    for (int j = 0; j < 16; j++) Wt[(c2 + j) * XSTR + r2] = __builtin_bit_cast(u16, (f16)wv[j]);
  }
  __syncthreads();

  if (w == 0) {
    // K fragments, SLOT-PERMUTED: frag (tau, ct), lane ln reads tile-local row
    // krow = (ln>>2)*8 + ct*4 + (ln&3).
#pragma unroll
    for (int ct = 0; ct < 2; ct++) {
      const int krow = (ln >> 2) * 8 + ct * 4 + (ln & 3);
      const long F = ((long)b * 128 + tau) * 2 + ct;
#pragma unroll
      for (int ks = 0; ks < 2; ks++) {
        f16x8 kv = *(const f16x8*)&Xs[krow * XSTR + ks * 32 + qd * 8];
        *(f16x8*)(Kswz + (F * 2 + ks) * FRAG + lane * 8) = kv;
      }
    }
    // V d-block 0
    {
      const long Cb = (long)b * 4 + 0;
      bf16x8 vv;
#pragma unroll
      for (int j = 0; j < 8; j++) {
        f16 hv = __builtin_bit_cast(f16, Xs[(qd * 8 + j) * XSTR + 0 * 16 + ln]);
        vv[j] = (__bf16)(float)hv;
      }
      *(bf16x8*)(Vswz + (Cb * (T_SEQ / 32) + tau) * FRAG + lane * 8) = vv;
    }
  } else if (w == 1) {
    // V d-blocks 1..3
#pragma unroll
    for (int db = 1; db < 4; db++) {
      const long Cb = (long)b * 4 + db;
      bf16x8 vv;
#pragma unroll
      for (int j = 0; j < 8; j++) {
        f16 hv = __builtin_bit_cast(f16, Xs[(qd * 8 + j) * XSTR + db * 16 + ln]);
        vv[j] = (__bf16)(float)hv;
      }
      *(bf16x8*)(Vswz + (Cb * (T_SEQ / 32) + tau) * FRAG + lane * 8) = vv;
    }
  } else {
    // Q rows (w-2)*16 .. +16: X@W via MFMA, scale by log2e, emit A-fragments
    const int h2 = w - 2;             // 0..1
    const int rq = h2 * 16;
    floatx4 acc[4];
#pragma unroll
    for (int ct = 0; ct < 4; ct++) acc[ct] = (floatx4)0.0f;
#pragma unroll
    for (int ks = 0; ks < 2; ks++) {
      f16x8 aX = *(const f16x8*)&Xs[(rq + ln) * XSTR + ks * 32 + qd * 8];
#pragma unroll
      for (int ct = 0; ct < 4; ct++) {
        f16x8 bW = *(const f16x8*)&Wt[(ct * 16 + ln) * XSTR + ks * 32 + qd * 8];
        acc[ct] = __builtin_amdgcn_mfma_f32_16x16x32_f16(aX, bW, acc[ct], 0, 0, 0);
      }
    }
#pragma unroll
    for (int ct = 0; ct < 4; ct++)
#pragma unroll
      for (int r = 0; r < 4; r++)
        Qs[h2][(qd * 4 + r) * XSTR + ct * 16 + ln] =
            __builtin_bit_cast(u16, (f16)(acc[ct][r] * LOG2E));
    // wave-local rows: no barrier needed
    const long R = (long)b * (T_SEQ / 16) + tau * 2 + h2;
#pragma unroll
    for (int ks = 0; ks < 2; ks++) {
      f16x8 qv = *(const f16x8*)&Qs[h2][ln * XSTR + ks * 32 + qd * 8];
      *(f16x8*)(Qswz + (R * 2 + ks) * FRAG + lane * 8) = qv;
    }
  }
}

// ---- main, ROUND 16: r9 base (best verified: 46.2 us) with two A/B'd edits:
//  (a) ALL s_setprio REMOVED. m190: setprio(1) around MFMA hurts lockstep
//      barriered loops (it deprioritizes waves in their memory/exp phase; it
//      pays only in role-split schedules, which this is not). Present in
//      every kernel since r3 — never isolated until now.
//  (b) l computed on the MFMA pipe: Ol[rb] = mfma(pk[rb], ones) gives the
//      P row-sums (every column identical). Deletes 16 v_add per wave-iter,
//      the 4 shfl_xor epilogue reduce, and lpart. l rides in Opart column 64
//      (the stride-68 pad), summed across wk like O itself.
// Ledger of nulls: barrier count (r12), cross-iter pipelining (r7/r8), tile
// size (r10), LDS size (r9), block count/split-K (r14), barrier-free (r15).
// All land 46-56 us, MfmaUtil+VALUBusy ~ 67%. If this round is also null
// (46 +- 1), the structure is at its issue/latency equilibrium.
// Rule #20: all register-array indices compile-time.
__launch_bounds__(512, 2)
__global__ void attn_kernel(const u16* __restrict__ Kswz, const u16* __restrict__ Qswz,
                            const u16* __restrict__ Vswz, float* __restrict__ out) {
  // smem: K dbuf 2 x 16 KB during main loop; epilogue Opart (34816 B) aliases
  __shared__ __attribute__((aligned(16))) char smem[35840];
  float* Opart = (float*)smem;

  const int tid = threadIdx.x;
  const int lane = tid & 63;
  const int w = tid >> 6;           // 0..7
  const int qd = lane >> 4;
  const int ln = lane & 15;
  const int wg = w >> 2;            // q-group
  const int wk = w & 3;             // key subgroup
  const int bid = blockIdx.x;
  const int b = bid & 7;            // batch == XCD for L2 affinity
  const int q0 = (bid >> 3) * QT;
  const long bbase = (long)b * T_SEQ * DIM;

  // Q B-fragments pinned: 32 rows x 64 d for this q-group
  f16x8 aQ[2][2];
#pragma unroll
  for (int rb = 0; rb < 2; rb++)
#pragma unroll
    for (int ks = 0; ks < 2; ks++)
      aQ[rb][ks] = *(const f16x8*)(Qswz +
          (((long)b * (T_SEQ / 16) + (q0 >> 4) + wg * 2 + rb) * 2 + ks) * FRAG + lane * 8);

  // ones B-fragment for the l row-sum MFMA
  bf16x8 vone;
#pragma unroll
  for (int j = 0; j < 8; j++) vone[j] = (__bf16)1.0f;

  // K stage source: wave w stages frags w*2, w*2+1 of the 16 per tile-group
  const char* gKw = (const char*)Kswz + (long)b * 524288 + (long)w * 2048 + lane * 16;
  // V direct source: frag (db, tile t*4+wk) at b*524288 + db*131072 + (t*4+wk)*1024
  const char* gV = (const char*)Vswz + (long)b * 524288 + (long)wk * 1024 + lane * 16;

#define STAGE(bufv, t)                                                                  \
  do {                                                                                  \
    const char* g_ = gKw + (long)(t) * 16384;                                           \
    char* l_ = smem + (bufv) * 16384 + w * 2048;                                        \
    __builtin_amdgcn_global_load_lds((gvoid*)(g_), (svoid*)(l_), 16, 0, 0);             \
    __builtin_amdgcn_global_load_lds((gvoid*)(g_ + 1024), (svoid*)(l_ + 1024), 16, 0, 0); \
  } while (0)

  floatx4 O[2][4];                  // [q 16-block][d 16-block], 32q x 64d per wave
  floatx4 Ol[2];                    // l row-sums (every column identical)
#pragma unroll
  for (int rb = 0; rb < 2; rb++) {
    Ol[rb] = (floatx4)0.0f;
#pragma unroll
    for (int db = 0; db < 4; db++) O[rb][db] = (floatx4)0.0f;
  }

  STAGE(0, 0);
  __syncthreads();

  int buf = 0;
#pragma unroll 1
  for (int t = 0; t < NIT; t++) {
    // V fragments: global loads FIRST (oldest in vmcnt queue -> PV's wait
    // leaves the younger stage loads outstanding)
    bf16x8 bV[4];
#pragma unroll
    for (int db = 0; db < 4; db++)
      bV[db] = *(const bf16x8*)(gV + (long)t * 4096 + (long)db * 131072);

    // prefetch next K tile-group into the other buffer (async)
    if (t + 1 < NIT) STAGE(buf ^ 1, t + 1);

    // K LDS -> registers (linear 1 KB fragments: conflict-free b128 reads)
    const char* Kb = smem + buf * 16384 + wk * 4096;
    f16x8 bK[2][2];
#pragma unroll
    for (int ct = 0; ct < 2; ct++)
#pragma unroll
      for (int ks = 0; ks < 2; ks++)
        bK[ct][ks] = *(const f16x8*)(Kb + (ct * 2 + ks) * 1024 + lane * 16);

    // QK^T: S^T[32k x 32q]
    floatx4 St[2][2];
#pragma unroll
    for (int ct = 0; ct < 2; ct++)
#pragma unroll
      for (int rb = 0; rb < 2; rb++) St[ct][rb] = (floatx4)0.0f;
#pragma unroll
    for (int ks = 0; ks < 2; ks++)
#pragma unroll
      for (int ct = 0; ct < 2; ct++)
#pragma unroll
        for (int rb = 0; rb < 2; rb++)
          St[ct][rb] = __builtin_amdgcn_mfma_f32_16x16x32_f16(bK[ct][ks], aQ[rb][ks], St[ct][rb], 0, 0, 0);

    // P = 2^S' in registers: slot (ct,qd,r) -> A-frag element j = ct*4 + r
    bf16x8 pk[2];
#pragma unroll
    for (int rb = 0; rb < 2; rb++)
#pragma unroll
      for (int ct = 0; ct < 2; ct++)
#pragma unroll
        for (int r = 0; r < 4; r++)
          pk[rb][ct * 4 + r] = (__bf16)EXP2(St[ct][rb][r]);

    // PV: O += P V ; l rides the MFMA pipe via the ones column
#pragma unroll
    for (int rb = 0; rb < 2; rb++) {
#pragma unroll
      for (int db = 0; db < 4; db++)
        O[rb][db] = __builtin_amdgcn_mfma_f32_16x16x32_bf16(pk[rb], bV[db], O[rb][db], 0, 0, 0);
      Ol[rb] = __builtin_amdgcn_mfma_f32_16x16x32_bf16(pk[rb], vone, Ol[rb], 0, 0, 0);
    }

    __syncthreads();  // drains vmcnt (next K tile staged) + lgkm; publishes buf^1
    buf ^= 1;
  }

  // epilogue: FULLY UNROLLED (rule #20). l lives in Opart column 64 (the
  // stride-68 pad): Ol[rb][r] = l[q-row qd*4+r], identical across ln.
#pragma unroll
  for (int rb = 0; rb < 2; rb++) {
    __syncthreads();  // rb=0: last K reads done (Opart aliases smem); rb=1: prior reads done
#pragma unroll
    for (int db = 0; db < 4; db++)
#pragma unroll
      for (int r = 0; r < 4; r++)
        Opart[(w * 16 + qd * 4 + r) * 68 + db * 16 + ln] = O[rb][db][r];
    if (ln == 0) {
#pragma unroll
      for (int r = 0; r < 4; r++)
        Opart[(w * 16 + qd * 4 + r) * 68 + 64] = Ol[rb][r];
    }
    __syncthreads();
    const int wg2 = tid >> 8;         // 0..1
    const int q2 = (tid >> 4) & 15;   // 0..15
    const int d0 = (tid & 15) * 4;    // 0..60
    float4 s = *(const float4*)&Opart[((wg2 * 4 + 0) * 16 + q2) * 68 + d0];
    const float4 s1 = *(const float4*)&Opart[((wg2 * 4 + 1) * 16 + q2) * 68 + d0];
    const float4 s2 = *(const float4*)&Opart[((wg2 * 4 + 2) * 16 + q2) * 68 + d0];
    const float4 s3 = *(const float4*)&Opart[((wg2 * 4 + 3) * 16 + q2) * 68 + d0];
    float l = Opart[((wg2 * 4 + 0) * 16 + q2) * 68 + 64] +
              Opart[((wg2 * 4 + 1) * 16 + q2) * 68 + 64] +
              Opart[((wg2 * 4 + 2) * 16 + q2) * 68 + 64] +
              Opart[((wg2 * 4 + 3) * 16 + q2) * 68 + 64];
    const float inv = 1.0f / l;
    float4 o;
    o.x = (s.x + s1.x + s2.x + s3.x) * inv;
    o.y = (s.y + s1.y + s2.y + s3.y) * inv;
    o.z = (s.z + s1.z + s2.z + s3.z) * inv;
    o.w = (s.w + s1.w + s2.w + s3.w) * inv;
    *(float4*)(out + bbase + (long)(q0 + wg2 * 32 + rb * 16 + q2) * DIM + d0) = o;
  }
#undef STAGE
}

extern "C" void kernel_launch(void* const* d_in, const int* in_sizes, int n_in,
                              void* d_out, int out_size, void* d_ws, size_t ws_size,
                              hipStream_t stream) {
  const float* X = (const float*)d_in[0];
  const float* W = (const float*)d_in[1];
  float* out = (float*)d_out;
  const size_t SZ = (size_t)B_N * T_SEQ * DIM * 2;  // 4 MB per u16 array
  u16* Kswz = (u16*)d_ws;
  u16* Qswz = (u16*)((char*)d_ws + SZ);
  u16* Vswz = (u16*)((char*)d_ws + 2 * SZ);
  prep_kernel<<<dim3(T_SEQ / 32, B_N), 256, 0, stream>>>(X, W, Kswz, Qswz, Vswz);
  attn_kernel<<<dim3(B_N * (T_SEQ / QT)), 512, 0, stream>>>(Kswz, Qswz, Vswz, out);
}